// Round 2
// baseline (11729.379 us; speedup 1.0000x reference)
//
#include <hip/hip_runtime.h>
#include <hip/hip_bf16.h>
#include <hip/hip_cooperative_groups.h>
#include <math.h>

#define MINN 1e-7f

// Problem dims (fixed by setup_inputs)
#define BB 64
#define SS 128
#define DD 768
#define HH 768
#define NCOL 3840            // 768 (W_d) + 4*768 (gates)
#define NWG_GEMM 240         // NCOL/16

namespace cg = cooperative_groups;

__device__ __forceinline__ float artanh_c(float x) {
  x = fminf(fmaxf(x, -1.0f + 1e-6f), 1.0f - 1e-6f);
  return atanhf(x);
}
__device__ __forceinline__ float tan_k_(float x, float sq) { return tanhf(sq * x) / sq; }
__device__ __forceinline__ float artan_k_(float x, float sq) { return artanh_c(sq * x) / sq; }

template <int N>
__device__ __forceinline__ void block_reduce_sum(float* v, float* red) {
#pragma unroll
  for (int m = 1; m < 64; m <<= 1) {
#pragma unroll
    for (int i = 0; i < N; ++i) v[i] += __shfl_xor(v[i], m, 64);
  }
  int wid = threadIdx.x >> 6;
  int lane = threadIdx.x & 63;
  if (lane == 0) {
#pragma unroll
    for (int i = 0; i < N; ++i) red[wid * N + i] = v[i];
  }
  __syncthreads();
#pragma unroll
  for (int i = 0; i < N; ++i) v[i] = red[i] + red[N + i] + red[2 * N + i] + red[3 * N + i];
  __syncthreads();
}

// Build combined weight matrix, chunked: CW[j][k][cc] = weight(k, col=j*16+cc)
__global__ __launch_bounds__(256) void k_build_cw(const float* __restrict__ W_all,
                                                  const float* __restrict__ W_d,
                                                  float* __restrict__ CW) {
  int j = blockIdx.x;
  float* dst = CW + (size_t)j * 12288;
  for (int idx = threadIdx.x; idx < 12288; idx += 256) {
    int k = idx >> 4;
    int cc = idx & 15;
    int col = j * 16 + cc;
    float v;
    if (col < 768) {
      v = W_d[col * 768 + k];
    } else {
      int jm = col - 768;
      int g = jm / 768;
      int j2 = jm - g * 768;
      v = W_all[j2 * 3072 + g * 768 + k];
    }
    dst[idx] = v;
  }
}

__global__ __launch_bounds__(256) void k_xnorm(const float* __restrict__ X,
                                               float* __restrict__ XN) {
  __shared__ float red[4];
  int r = blockIdx.x;
  float s = 0.f;
#pragma unroll
  for (int p = 0; p < 3; ++p) {
    float v = X[(size_t)r * 768 + threadIdx.x + 256 * p];
    s += v * v;
  }
#pragma unroll
  for (int m = 1; m < 64; m <<= 1) s += __shfl_xor(s, m, 64);
  if ((threadIdx.x & 63) == 0) red[threadIdx.x >> 6] = s;
  __syncthreads();
  if (threadIdx.x == 0) XN[r] = fmaxf(sqrtf(red[0] + red[1] + red[2] + red[3]), MINN);
}

// C[i][m] = sum_k X[i][k] * U[m][k];  M=8192, N=3072, K=768. Output bf16.
__global__ __launch_bounds__(256) void k_gemm_xu(const float* __restrict__ X,
                                                 const float* __restrict__ U,
                                                 __hip_bfloat16* __restrict__ OUT) {
  __shared__ float As[64][17];
  __shared__ float Bs[64][17];
  int tid = threadIdx.x;
  int lr = tid >> 2;
  int lk = (tid & 3) * 4;
  int tm = tid & 15;
  int ti = tid >> 4;
  const float* xr = X + (size_t)(blockIdx.x * 64 + lr) * 768 + lk;
  const float* ur = U + (size_t)(blockIdx.y * 64 + lr) * 768 + lk;
  float acc[4][4];
#pragma unroll
  for (int a = 0; a < 4; ++a)
#pragma unroll
    for (int b = 0; b < 4; ++b) acc[a][b] = 0.f;

  for (int kt = 0; kt < 768; kt += 16) {
    float4 a = *(const float4*)(xr + kt);
    float4 b = *(const float4*)(ur + kt);
    As[lr][lk + 0] = a.x; As[lr][lk + 1] = a.y; As[lr][lk + 2] = a.z; As[lr][lk + 3] = a.w;
    Bs[lr][lk + 0] = b.x; Bs[lr][lk + 1] = b.y; Bs[lr][lk + 2] = b.z; Bs[lr][lk + 3] = b.w;
    __syncthreads();
#pragma unroll
    for (int k = 0; k < 16; ++k) {
      float av[4], bv[4];
#pragma unroll
      for (int q = 0; q < 4; ++q) {
        av[q] = As[ti * 4 + q][k];
        bv[q] = Bs[tm * 4 + q][k];
      }
#pragma unroll
      for (int rr = 0; rr < 4; ++rr)
#pragma unroll
        for (int c2 = 0; c2 < 4; ++c2) acc[rr][c2] += av[rr] * bv[c2];
    }
    __syncthreads();
  }
#pragma unroll
  for (int rr = 0; rr < 4; ++rr)
#pragma unroll
    for (int c2 = 0; c2 < 4; ++c2)
      OUT[(size_t)(blockIdx.x * 64 + ti * 4 + rr) * 3072 + blockIdx.y * 64 + tm * 4 + c2] =
          __float2bfloat16(acc[rr][c2]);
}

// Persistent cooperative scan kernel: 240 WGs.
// Phase A (all WGs): GOUT[row][col] = sum_k state[k][row] * Wl[k][c], weights LDS-resident.
// Phase B (WGs 0..63): hyperbolic pointwise update; c/h state lives in registers.
__global__ __launch_bounds__(256, 1) void k_scan(
    const float* __restrict__ CW, float* __restrict__ ccT, float* __restrict__ hT,
    float* __restrict__ GOUT, const __hip_bfloat16* __restrict__ UG,
    const float* __restrict__ XN, const float* __restrict__ TS,
    const float* __restrict__ kptr, const float* __restrict__ h0,
    const float* __restrict__ c0, float* __restrict__ out) {
  cg::grid_group grid = cg::this_grid();
  __shared__ float Wl[12288];  // 48 KB weight chunk, resident across all 128 steps
  __shared__ float red[64];
  int wg = blockIdx.x;
  int tid = threadIdx.x;

  // Load this WG's weight chunk once.
  {
    const float4* s4 = (const float4*)(CW + (size_t)wg * 12288);
    float4* d4 = (float4*)Wl;
#pragma unroll
    for (int it = 0; it < 12; ++it) d4[tid + 256 * it] = s4[tid + 256 * it];
  }

  float kk = kptr[0];
  float sq = sqrtf(-kk);
  int r = wg;  // row owned in phase B (wg < 64 only)

  // Register-resident recurrent state for phase B owners.
  float cc[3], h[3];
  if (wg < BB) {
#pragma unroll
    for (int p = 0; p < 3; ++p) {
      int j = tid + 256 * p;
      cc[p] = c0[r * 768 + j];
      h[p] = h0[r * 768 + j];
      ccT[j * 64 + r] = cc[p];
      hT[j * 64 + r] = h[p];
    }
  }
  grid.sync();

  for (int t = 0; t < SS; ++t) {
    // ---------------- Phase A: recurrent GEMM (all 240 WGs) ----------------
    {
      const float* src = (wg < 48) ? ccT : hT;
      int c = tid & 15;
      int rg = tid >> 4;
      const float* sp = src + 4 * rg;
      float a0 = 0.f, a1 = 0.f, a2 = 0.f, a3 = 0.f;
#pragma unroll 8
      for (int k = 0; k < 768; ++k) {
        float4 s = *(const float4*)(sp + (size_t)k * 64);
        float w = Wl[k * 16 + c];
        a0 += s.x * w;
        a1 += s.y * w;
        a2 += s.z * w;
        a3 += s.w * w;
      }
      int col = wg * 16 + c;
      GOUT[(4 * rg + 0) * NCOL + col] = a0;
      GOUT[(4 * rg + 1) * NCOL + col] = a1;
      GOUT[(4 * rg + 2) * NCOL + col] = a2;
      GOUT[(4 * rg + 3) * NCOL + col] = a3;
    }
    grid.sync();

    // ---------------- Phase B: pointwise hyperbolic update (WGs 0..63) ------
    if (wg < BB) {
      const float* grow = GOUT + r * NCOL;
      int i = r * SS + t;
      const __hip_bfloat16* urow = UG + (size_t)i * 3072;

      float mv[3], gh[4][3], mx[4][3];
#pragma unroll
      for (int p = 0; p < 3; ++p) {
        int j = tid + 256 * p;
        mv[p] = grow[j];
#pragma unroll
        for (int g = 0; g < 4; ++g) {
          gh[g][p] = grow[768 + g * 768 + j];
          mx[g][p] = __bfloat162float(urow[g * 768 + j]);
        }
      }

      // batch1: {c2, h2, mvn2, |gh_g|^2 x4, gh_g.mx_g x4, |mx_g|^2 x4}
      float sv[15];
#pragma unroll
      for (int q = 0; q < 15; ++q) sv[q] = 0.f;
#pragma unroll
      for (int p = 0; p < 3; ++p) {
        sv[0] += cc[p] * cc[p];
        sv[1] += h[p] * h[p];
        sv[2] += mv[p] * mv[p];
#pragma unroll
        for (int g = 0; g < 4; ++g) {
          sv[3 + g] += gh[g][p] * gh[g][p];
          sv[7 + g] += gh[g][p] * mx[g][p];
          sv[11 + g] += mx[g][p] * mx[g][p];
        }
      }
      block_reduce_sum<15>(sv, red);
      float c2 = sv[0], h2 = sv[1], mvn2 = sv[2];
      float xn_c = fmaxf(sqrtf(c2), MINN);
      float xn_h = fmaxf(sqrtf(h2), MINN);
      float mxn_d = fmaxf(sqrtf(mvn2), MINN);

      // W_d path: l = logmap0(mobius_matvec(W_d, cc)), th = tanh(l)
      float r_d = (mxn_d / xn_c) * artan_k_(xn_c, sq);
      float twd = tan_k_(r_d, sq);
      float wdsc = twd / mxn_d;
      float yn_d = fmaxf(fabsf(twd), MINN);
      float lsc = (artan_k_(yn_d, sq) / yn_d) * wdsc;
      float th[3];
#pragma unroll
      for (int p = 0; p < 3; ++p) th[p] = tanhf(lsc * mv[p]);

      // gates: sigmoid(logmap0(mobius_add(Wmv_g, Umv_g)))
      float uxn = XN[i];
      float ak_h = artan_k_(xn_h, sq);
      float ak_u = artan_k_(uxn, sq);
      float cAg[4], cBg[4], pscg[4];
#pragma unroll
      for (int g = 0; g < 4; ++g) {
        float ghn = fmaxf(sqrtf(sv[3 + g]), MINN);
        float tg = tan_k_((ghn / xn_h) * ak_h, sq);
        float wsc = tg / ghn;
        float w2 = tg * tg;
        float umxn = fmaxf(sqrtf(sv[11 + g]), MINN);
        float us = tan_k_((umxn / uxn) * ak_u, sq) / umxn;
        float u2 = us * us * sv[11 + g];
        float xy = wsc * us * sv[7 + g];
        float den = fmaxf(1.f - 2.f * kk * xy + kk * kk * w2 * u2, MINN);
        float a = (1.f - 2.f * kk * xy - kk * u2) / den;
        float b = (1.f + kk * w2) / den;
        float y2s = fmaxf(a * a * w2 + 2.f * a * b * xy + b * b * u2, 0.f);
        float yn = fmaxf(sqrtf(y2s), MINN);
        pscg[g] = artan_k_(yn, sq) / yn;
        cAg[g] = a * wsc;
        cBg[g] = b * us;
      }
      float gate[4][3];
#pragma unroll
      for (int g = 0; g < 4; ++g)
#pragma unroll
        for (int p = 0; p < 3; ++p)
          gate[g][p] = 1.f / (1.f + expf(-pscg[g] * (cAg[g] * gh[g][p] + cBg[g] * mx[g][p])));

      // batch2: {|th|^2, th.cc}
      float s2v[2] = {0.f, 0.f};
#pragma unroll
      for (int p = 0; p < 3; ++p) {
        s2v[0] += th[p] * th[p];
        s2v[1] += th[p] * cc[p];
      }
      block_reduce_sum<2>(s2v, red);
      float un = fmaxf(sqrtf(s2v[0]), MINN);
      float esc = tan_k_(un, sq) / un;
      float cs1[3];
#pragma unroll
      for (int p = 0; p < 3; ++p) cs1[p] = esc * th[p];
      float d1 = esc * s2v[1];          // cs1 . cc
      float s1sq = esc * esc * s2v[0];  // |cs1|^2

      // c_s2 = mobius_pmul(c_s1, t_exp) = s2s * cs1
      float tv = TS[r * SS + t];
      float xnt = fmaxf(sqrtf(768.f * tv * tv), MINN);
      float wxn_t = fmaxf(fabsf(tv) * sqrtf(s1sq), MINN);
      float s2s = tan_k_((wxn_t / xnt) * artan_k_(xnt, sq), sq) / wxn_t * tv;
      float s2sq = s2s * s2s * s1sq;

      // c_l = mobius_add(-cs1, cc)
      float den_l = fmaxf(1.f + 2.f * kk * d1 + kk * kk * s1sq * c2, MINN);
      float al = (1.f + 2.f * kk * d1 - kk * c2) / den_l;
      float bl = (1.f + kk * s1sq) / den_l;
      float pcl = -al, qcl = bl;

      // c_adj = mobius_add(c_l, c_s2)
      float xy2 = s2s * (pcl * s1sq + qcl * d1);
      float x2b = fmaxf(pcl * pcl * s1sq + 2.f * pcl * qcl * d1 + qcl * qcl * c2, 0.f);
      float y2b = s2sq;
      float den2 = fmaxf(1.f - 2.f * kk * xy2 + kk * kk * x2b * y2b, MINN);
      float a2 = (1.f - 2.f * kk * xy2 - kk * y2b) / den2;
      float b2 = (1.f + kk * x2b) / den2;
      float g1c = a2 * pcl + b2 * s2s;
      float g2c = a2 * qcl;
      float cadj[3];
#pragma unroll
      for (int p = 0; p < 3; ++p) cadj[p] = g1c * cs1[p] + g2c * cc[p];
      float adjsq = fmaxf(g1c * g1c * s1sq + 2.f * g1c * g2c * d1 + g2c * g2c * c2, 0.f);

      // P_i = pmul(i, c_tmp), P_f = pmul(f, c_adj), new_c = madd(P_i, P_f)
      float wxi[3], wxf[3];
#pragma unroll
      for (int p = 0; p < 3; ++p) {
        wxi[p] = gate[1][p] * gate[3][p];
        wxf[p] = gate[0][p] * cadj[p];
      }
      float s3v[4] = {0.f, 0.f, 0.f, 0.f};
#pragma unroll
      for (int p = 0; p < 3; ++p) {
        s3v[0] += gate[3][p] * gate[3][p];
        s3v[1] += wxi[p] * wxi[p];
        s3v[2] += wxf[p] * wxf[p];
        s3v[3] += wxi[p] * wxf[p];
      }
      block_reduce_sum<4>(s3v, red);
      float xnct = fmaxf(sqrtf(s3v[0]), MINN);
      float wxni = fmaxf(sqrtf(s3v[1]), MINN);
      float psi = tan_k_((wxni / xnct) * artan_k_(xnct, sq), sq) / wxni;
      float pi2 = psi * psi * s3v[1];
      float xnadj = fmaxf(sqrtf(adjsq), MINN);
      float wxnf = fmaxf(sqrtf(s3v[2]), MINN);
      float psf = tan_k_((wxnf / xnadj) * artan_k_(xnadj, sq), sq) / wxnf;
      float pf2 = psf * psf * s3v[2];
      float xyp = psi * psf * s3v[3];
      float den3 = fmaxf(1.f - 2.f * kk * xyp + kk * kk * pi2 * pf2, MINN);
      float a3 = (1.f - 2.f * kk * xyp - kk * pf2) / den3;
      float b3 = (1.f + kk * pi2) / den3;
      float nc[3], tc[3];
#pragma unroll
      for (int p = 0; p < 3; ++p) {
        nc[p] = a3 * psi * wxi[p] + b3 * psf * wxf[p];
        tc[p] = tanhf(nc[p]);
      }
      float s4v[1] = {0.f};
#pragma unroll
      for (int p = 0; p < 3; ++p) s4v[0] += tc[p] * tc[p];
      block_reduce_sum<1>(s4v, red);
      float unh = fmaxf(sqrtf(s4v[0]), MINN);
      float ehs = tan_k_(unh, sq) / unh;
      float Esq = ehs * ehs * s4v[0];
      float En = fmaxf(sqrtf(Esq), MINN);
      float wxo[3];
#pragma unroll
      for (int p = 0; p < 3; ++p) wxo[p] = gate[2][p] * (ehs * tc[p]);
      float s5v[1] = {0.f};
#pragma unroll
      for (int p = 0; p < 3; ++p) s5v[0] += wxo[p] * wxo[p];
      block_reduce_sum<1>(s5v, red);
      float wxno = fmaxf(sqrtf(s5v[0]), MINN);
      float pso = tan_k_((wxno / En) * artan_k_(En, sq), sq) / wxno;

      size_t BSHc = (size_t)BB * SS * HH;
#pragma unroll
      for (int p = 0; p < 3; ++p) {
        int j = tid + 256 * p;
        out[((size_t)r * SS + t) * HH + j] = gate[2][p];  // output = o gate
        float ncv = nc[p];
        float nhv = pso * wxo[p];
        cc[p] = ncv;
        h[p] = nhv;
        ccT[j * 64 + r] = ncv;
        hT[j * 64 + r] = nhv;
        if (t == SS - 1) {
          out[BSHc + (size_t)r * HH + j] = nhv;                    // h_last
          out[BSHc + (size_t)BB * HH + (size_t)r * HH + j] = ncv;  // c_last
        }
      }
    }
    grid.sync();
  }
}

extern "C" void kernel_launch(void* const* d_in, const int* in_sizes, int n_in,
                              void* d_out, int out_size, void* d_ws, size_t ws_size,
                              hipStream_t stream) {
  const float* inputs = (const float*)d_in[0];
  const float* ts = (const float*)d_in[1];
  const float* h0 = (const float*)d_in[2];
  const float* c0 = (const float*)d_in[3];
  const float* W_all = (const float*)d_in[4];
  const float* U_all = (const float*)d_in[5];
  const float* W_d = (const float*)d_in[6];
  const float* kptr = (const float*)d_in[7];
  float* ws = (float*)d_ws;
  float* out = (float*)d_out;

  size_t oCW = 0;
  size_t oCCT = oCW + (size_t)NWG_GEMM * 12288;  // 2,949,120
  size_t oHT = oCCT + 49152;
  size_t oGOUT = oHT + 49152;
  size_t oXN = oGOUT + (size_t)BB * NCOL;  // 245,760
  size_t oUG = oXN + 8192;

  float* cw = ws + oCW;
  float* cct = ws + oCCT;
  float* ht = ws + oHT;
  float* gout = ws + oGOUT;
  float* xn = ws + oXN;
  __hip_bfloat16* ug = (__hip_bfloat16*)(ws + oUG);

  k_build_cw<<<NWG_GEMM, 256, 0, stream>>>(W_all, W_d, cw);
  k_gemm_xu<<<dim3(128, 48), 256, 0, stream>>>(inputs, U_all, ug);
  k_xnorm<<<BB * SS, 256, 0, stream>>>(inputs, xn);

  void* args[] = {(void*)&cw,   (void*)&cct, (void*)&ht,   (void*)&gout,
                  (void*)&ug,   (void*)&xn,  (void*)&ts,   (void*)&kptr,
                  (void*)&h0,   (void*)&c0,  (void*)&out};
  hipLaunchCooperativeKernel((void*)k_scan, dim3(NWG_GEMM), dim3(256), args, 0, stream);
}

// Round 3
// 10867.734 us; speedup vs baseline: 1.0793x; 1.0793x over previous
//
#include <hip/hip_runtime.h>
#include <hip/hip_bf16.h>
#include <math.h>

#define MINN 1e-7f

// Problem dims (fixed by setup_inputs)
#define BB 64
#define SS 128
#define NCOL 3840            // 768 (W_d) + 4*768 (gates)
#define NWG 240              // NCOL/16

__device__ __forceinline__ float artanh_c(float x) {
  x = fminf(fmaxf(x, -1.0f + 1e-6f), 1.0f - 1e-6f);
  return atanhf(x);
}
__device__ __forceinline__ float tan_k_(float x, float sq) { return tanhf(sq * x) / sq; }
__device__ __forceinline__ float artan_k_(float x, float sq) { return artanh_c(sq * x) / sq; }

// Block reduction over 512 threads (8 waves).
template <int N>
__device__ __forceinline__ void block_reduce_sum8(float* v, float* red) {
#pragma unroll
  for (int m = 1; m < 64; m <<= 1) {
#pragma unroll
    for (int i = 0; i < N; ++i) v[i] += __shfl_xor(v[i], m, 64);
  }
  int wid = threadIdx.x >> 6;
  int lane = threadIdx.x & 63;
  if (lane == 0) {
#pragma unroll
    for (int i = 0; i < N; ++i) red[wid * N + i] = v[i];
  }
  __syncthreads();
#pragma unroll
  for (int i = 0; i < N; ++i) {
    float s = 0.f;
#pragma unroll
    for (int w = 0; w < 8; ++w) s += red[w * N + i];
    v[i] = s;
  }
  __syncthreads();
}

// Lightweight grid barrier: monotonic counter, device-scope.
__device__ __forceinline__ void gbar(unsigned int* bar, unsigned int target) {
  __syncthreads();
  if (threadIdx.x == 0) {
    __threadfence();           // release: make our global writes visible device-wide
    atomicAdd(bar, 1u);        // device-scope by default on CDNA
    while (__hip_atomic_load(bar, __ATOMIC_RELAXED, __HIP_MEMORY_SCOPE_AGENT) < target) {
      __builtin_amdgcn_s_sleep(2);
    }
    __threadfence();           // acquire
  }
  __syncthreads();
}

// Build combined weight matrix, chunked: CW[j][k][cc] = weight(k, col=j*16+cc)
__global__ __launch_bounds__(256) void k_build_cw(const float* __restrict__ W_all,
                                                  const float* __restrict__ W_d,
                                                  float* __restrict__ CW) {
  int j = blockIdx.x;
  float* dst = CW + (size_t)j * 12288;
  for (int idx = threadIdx.x; idx < 12288; idx += 256) {
    int k = idx >> 4;
    int cc = idx & 15;
    int col = j * 16 + cc;
    float v;
    if (col < 768) {
      v = W_d[col * 768 + k];
    } else {
      int jm = col - 768;
      int g = jm / 768;
      int j2 = jm - g * 768;
      v = W_all[j2 * 3072 + g * 768 + k];
    }
    dst[idx] = v;
  }
}

__global__ __launch_bounds__(256) void k_xnorm(const float* __restrict__ X,
                                               float* __restrict__ XN) {
  __shared__ float red[4];
  int r = blockIdx.x;
  float s = 0.f;
#pragma unroll
  for (int p = 0; p < 3; ++p) {
    float v = X[(size_t)r * 768 + threadIdx.x + 256 * p];
    s += v * v;
  }
#pragma unroll
  for (int m = 1; m < 64; m <<= 1) s += __shfl_xor(s, m, 64);
  if ((threadIdx.x & 63) == 0) red[threadIdx.x >> 6] = s;
  __syncthreads();
  if (threadIdx.x == 0) XN[r] = fmaxf(sqrtf(red[0] + red[1] + red[2] + red[3]), MINN);
}

// C[i][m] = sum_k X[i][k] * U[m][k];  M=8192, N=3072, K=768. Output bf16.
__global__ __launch_bounds__(256) void k_gemm_xu(const float* __restrict__ X,
                                                 const float* __restrict__ U,
                                                 __hip_bfloat16* __restrict__ OUT) {
  __shared__ float As[64][17];
  __shared__ float Bs[64][17];
  int tid = threadIdx.x;
  int lr = tid >> 2;
  int lk = (tid & 3) * 4;
  int tm = tid & 15;
  int ti = tid >> 4;
  const float* xr = X + (size_t)(blockIdx.x * 64 + lr) * 768 + lk;
  const float* ur = U + (size_t)(blockIdx.y * 64 + lr) * 768 + lk;
  float acc[4][4];
#pragma unroll
  for (int a = 0; a < 4; ++a)
#pragma unroll
    for (int b = 0; b < 4; ++b) acc[a][b] = 0.f;

  for (int kt = 0; kt < 768; kt += 16) {
    float4 a = *(const float4*)(xr + kt);
    float4 b = *(const float4*)(ur + kt);
    As[lr][lk + 0] = a.x; As[lr][lk + 1] = a.y; As[lr][lk + 2] = a.z; As[lr][lk + 3] = a.w;
    Bs[lr][lk + 0] = b.x; Bs[lr][lk + 1] = b.y; Bs[lr][lk + 2] = b.z; Bs[lr][lk + 3] = b.w;
    __syncthreads();
#pragma unroll
    for (int k = 0; k < 16; ++k) {
      float av[4], bv[4];
#pragma unroll
      for (int q = 0; q < 4; ++q) {
        av[q] = As[ti * 4 + q][k];
        bv[q] = Bs[tm * 4 + q][k];
      }
#pragma unroll
      for (int rr = 0; rr < 4; ++rr)
#pragma unroll
        for (int c2 = 0; c2 < 4; ++c2) acc[rr][c2] += av[rr] * bv[c2];
    }
    __syncthreads();
  }
#pragma unroll
  for (int rr = 0; rr < 4; ++rr)
#pragma unroll
    for (int c2 = 0; c2 < 4; ++c2)
      OUT[(size_t)(blockIdx.x * 64 + ti * 4 + rr) * 3072 + blockIdx.y * 64 + tm * 4 + c2] =
          __float2bfloat16(acc[rr][c2]);
}

// Persistent scan: 240 WGs x 512 threads, custom grid barrier.
// Phase A (all WGs): 16 cols each, k split across thread halves, 2-deep load pipeline.
// Phase B (WGs 0..63): hyperbolic pointwise update; c/h state in registers (2 elem/thread).
__global__ __launch_bounds__(512, 1) void k_scan(
    const float* __restrict__ CW, float* __restrict__ ccT, float* __restrict__ hT,
    float* __restrict__ GOUT, const __hip_bfloat16* __restrict__ UG,
    const float* __restrict__ XN, const float* __restrict__ TS,
    const float* __restrict__ kptr, const float* __restrict__ h0,
    const float* __restrict__ c0, float* __restrict__ out, unsigned int* __restrict__ bar) {
  __shared__ float Wl[12288];    // 48 KB weight chunk, resident across all steps
  __shared__ float4 Pacc[512];   // 8 KB phase-A partial combine
  __shared__ float red[8 * 15];  // reductions
  int wg = blockIdx.x;
  int tid = threadIdx.x;

  // Load this WG's weight chunk once (512 threads x 6 float4).
  {
    const float4* s4 = (const float4*)(CW + (size_t)wg * 12288);
    float4* d4 = (float4*)Wl;
#pragma unroll
    for (int it = 0; it < 6; ++it) d4[tid + 512 * it] = s4[tid + 512 * it];
  }

  float kk = kptr[0];
  float sq = sqrtf(-kk);
  int r = wg;                 // row owned in phase B (wg < 64 only)
  bool full = tid < 256;      // second element (j1) valid
  int j0 = tid, j1 = 512 + tid;

  // Register-resident recurrent state for phase B owners.
  float cc0 = 0.f, cc1 = 0.f, h_0 = 0.f, h_1 = 0.f;
  if (wg < BB) {
    cc0 = c0[r * 768 + j0];
    h_0 = h0[r * 768 + j0];
    ccT[j0 * 64 + r] = cc0;
    hT[j0 * 64 + r] = h_0;
    if (full) {
      cc1 = c0[r * 768 + j1];
      h_1 = h0[r * 768 + j1];
      ccT[j1 * 64 + r] = cc1;
      hT[j1 * 64 + r] = h_1;
    }
  }
  unsigned int barn = 0;
  gbar(bar, NWG * (++barn));

  for (int t = 0; t < SS; ++t) {
    // ---------------- Phase A: recurrent GEMM (all 240 WGs) ----------------
    {
      const float* src = (wg < 48) ? ccT : hT;
      int c = tid & 15;
      int rg = (tid >> 4) & 15;
      int kh = tid >> 8;  // 0 or 1: k-half
      const float4* sp = ((const float4*)src) + rg;  // element k at sp[k*16]
      const int kbase = kh * 384;
      float a0 = 0.f, a1 = 0.f, a2 = 0.f, a3 = 0.f;
      float4 bufA[8], bufB[8];
#pragma unroll
      for (int i = 0; i < 8; ++i) bufA[i] = sp[(kbase + i) * 16];
      for (int kb = 0; kb < 48; kb += 2) {
#pragma unroll
        for (int i = 0; i < 8; ++i) bufB[i] = sp[(kbase + (kb + 1) * 8 + i) * 16];
#pragma unroll
        for (int i = 0; i < 8; ++i) {
          int k = kbase + kb * 8 + i;
          float w = Wl[k * 16 + c];
          a0 += bufA[i].x * w; a1 += bufA[i].y * w; a2 += bufA[i].z * w; a3 += bufA[i].w * w;
        }
        if (kb + 2 < 48) {
#pragma unroll
          for (int i = 0; i < 8; ++i) bufA[i] = sp[(kbase + (kb + 2) * 8 + i) * 16];
        }
#pragma unroll
        for (int i = 0; i < 8; ++i) {
          int k = kbase + (kb + 1) * 8 + i;
          float w = Wl[k * 16 + c];
          a0 += bufB[i].x * w; a1 += bufB[i].y * w; a2 += bufB[i].z * w; a3 += bufB[i].w * w;
        }
      }
      Pacc[tid] = make_float4(a0, a1, a2, a3);
      __syncthreads();
      if (tid < 256) {
        float4 p0 = Pacc[tid];
        float4 p1 = Pacc[tid + 256];
        int col = wg * 16 + (tid & 15);
        int rg2 = tid >> 4;
        GOUT[(4 * rg2 + 0) * NCOL + col] = p0.x + p1.x;
        GOUT[(4 * rg2 + 1) * NCOL + col] = p0.y + p1.y;
        GOUT[(4 * rg2 + 2) * NCOL + col] = p0.z + p1.z;
        GOUT[(4 * rg2 + 3) * NCOL + col] = p0.w + p1.w;
      }
    }
    gbar(bar, NWG * (++barn));

    // ---------------- Phase B: pointwise hyperbolic update (WGs 0..63) ------
    if (wg < BB) {
      const float* grow = GOUT + r * NCOL;
      int i = r * SS + t;
      const __hip_bfloat16* urow = UG + (size_t)i * 3072;

      float mv0, mv1, gh0[4], gh1[4], mx0[4], mx1[4];
      mv0 = grow[j0];
      mv1 = full ? grow[j1] : 0.f;
#pragma unroll
      for (int g = 0; g < 4; ++g) {
        gh0[g] = grow[768 + g * 768 + j0];
        gh1[g] = full ? grow[768 + g * 768 + j1] : 0.f;
        mx0[g] = __bfloat162float(urow[g * 768 + j0]);
        mx1[g] = full ? __bfloat162float(urow[g * 768 + j1]) : 0.f;
      }

      // batch1: {c2, h2, mvn2, |gh_g|^2 x4, gh_g.mx_g x4, |mx_g|^2 x4}
      float sv[15];
#pragma unroll
      for (int q = 0; q < 15; ++q) sv[q] = 0.f;
      sv[0] = cc0 * cc0 + cc1 * cc1;
      sv[1] = h_0 * h_0 + h_1 * h_1;
      sv[2] = mv0 * mv0 + mv1 * mv1;
#pragma unroll
      for (int g = 0; g < 4; ++g) {
        sv[3 + g] = gh0[g] * gh0[g] + gh1[g] * gh1[g];
        sv[7 + g] = gh0[g] * mx0[g] + gh1[g] * mx1[g];
        sv[11 + g] = mx0[g] * mx0[g] + mx1[g] * mx1[g];
      }
      block_reduce_sum8<15>(sv, red);
      float c2 = sv[0], h2 = sv[1], mvn2 = sv[2];
      float xn_c = fmaxf(sqrtf(c2), MINN);
      float xn_h = fmaxf(sqrtf(h2), MINN);
      float mxn_d = fmaxf(sqrtf(mvn2), MINN);

      // W_d path
      float r_d = (mxn_d / xn_c) * artan_k_(xn_c, sq);
      float twd = tan_k_(r_d, sq);
      float wdsc = twd / mxn_d;
      float yn_d = fmaxf(fabsf(twd), MINN);
      float lsc = (artan_k_(yn_d, sq) / yn_d) * wdsc;
      float th0 = tanhf(lsc * mv0);
      float th1 = tanhf(lsc * mv1);

      // gates
      float uxn = XN[i];
      float ak_h = artan_k_(xn_h, sq);
      float ak_u = artan_k_(uxn, sq);
      float cAg[4], cBg[4], pscg[4];
#pragma unroll
      for (int g = 0; g < 4; ++g) {
        float ghn = fmaxf(sqrtf(sv[3 + g]), MINN);
        float tg = tan_k_((ghn / xn_h) * ak_h, sq);
        float wsc = tg / ghn;
        float w2 = tg * tg;
        float umxn = fmaxf(sqrtf(sv[11 + g]), MINN);
        float us = tan_k_((umxn / uxn) * ak_u, sq) / umxn;
        float u2 = us * us * sv[11 + g];
        float xy = wsc * us * sv[7 + g];
        float den = fmaxf(1.f - 2.f * kk * xy + kk * kk * w2 * u2, MINN);
        float a = (1.f - 2.f * kk * xy - kk * u2) / den;
        float b = (1.f + kk * w2) / den;
        float y2s = fmaxf(a * a * w2 + 2.f * a * b * xy + b * b * u2, 0.f);
        float yn = fmaxf(sqrtf(y2s), MINN);
        pscg[g] = artan_k_(yn, sq) / yn;
        cAg[g] = a * wsc;
        cBg[g] = b * us;
      }
      float gate0[4], gate1[4];
#pragma unroll
      for (int g = 0; g < 4; ++g) {
        gate0[g] = 1.f / (1.f + expf(-pscg[g] * (cAg[g] * gh0[g] + cBg[g] * mx0[g])));
        gate1[g] = 1.f / (1.f + expf(-pscg[g] * (cAg[g] * gh1[g] + cBg[g] * mx1[g])));
      }

      // batch2: {|th|^2, th.cc}
      float s2v[2];
      s2v[0] = th0 * th0 + th1 * th1;
      s2v[1] = th0 * cc0 + th1 * cc1;
      block_reduce_sum8<2>(s2v, red);
      float un = fmaxf(sqrtf(s2v[0]), MINN);
      float esc = tan_k_(un, sq) / un;
      float cs1_0 = esc * th0, cs1_1 = esc * th1;
      float d1 = esc * s2v[1];
      float s1sq = esc * esc * s2v[0];

      // c_s2 = s2s * cs1
      float tv = TS[r * SS + t];
      float xnt = fmaxf(sqrtf(768.f * tv * tv), MINN);
      float wxn_t = fmaxf(fabsf(tv) * sqrtf(s1sq), MINN);
      float s2s = tan_k_((wxn_t / xnt) * artan_k_(xnt, sq), sq) / wxn_t * tv;
      float s2sq = s2s * s2s * s1sq;

      // c_l = mobius_add(-cs1, cc)
      float den_l = fmaxf(1.f + 2.f * kk * d1 + kk * kk * s1sq * c2, MINN);
      float al = (1.f + 2.f * kk * d1 - kk * c2) / den_l;
      float bl = (1.f + kk * s1sq) / den_l;
      float pcl = -al, qcl = bl;

      // c_adj = mobius_add(c_l, c_s2)
      float xy2 = s2s * (pcl * s1sq + qcl * d1);
      float x2b = fmaxf(pcl * pcl * s1sq + 2.f * pcl * qcl * d1 + qcl * qcl * c2, 0.f);
      float y2b = s2sq;
      float den2 = fmaxf(1.f - 2.f * kk * xy2 + kk * kk * x2b * y2b, MINN);
      float a2 = (1.f - 2.f * kk * xy2 - kk * y2b) / den2;
      float b2 = (1.f + kk * x2b) / den2;
      float g1c = a2 * pcl + b2 * s2s;
      float g2c = a2 * qcl;
      float cadj0 = g1c * cs1_0 + g2c * cc0;
      float cadj1 = g1c * cs1_1 + g2c * cc1;
      float adjsq = fmaxf(g1c * g1c * s1sq + 2.f * g1c * g2c * d1 + g2c * g2c * c2, 0.f);

      // new_c = madd(pmul(i,c_tmp), pmul(f,c_adj))
      float wxi0 = gate0[1] * gate0[3], wxi1 = gate1[1] * gate1[3];
      float wxf0 = gate0[0] * cadj0, wxf1 = gate1[0] * cadj1;
      float s3v[4];
      s3v[0] = gate0[3] * gate0[3];
      s3v[1] = wxi0 * wxi0;
      s3v[2] = wxf0 * wxf0;
      s3v[3] = wxi0 * wxf0;
      if (full) {
        s3v[0] += gate1[3] * gate1[3];
        s3v[1] += wxi1 * wxi1;
        s3v[2] += wxf1 * wxf1;
        s3v[3] += wxi1 * wxf1;
      }
      block_reduce_sum8<4>(s3v, red);
      float xnct = fmaxf(sqrtf(s3v[0]), MINN);
      float wxni = fmaxf(sqrtf(s3v[1]), MINN);
      float psi = tan_k_((wxni / xnct) * artan_k_(xnct, sq), sq) / wxni;
      float pi2 = psi * psi * s3v[1];
      float xnadj = fmaxf(sqrtf(adjsq), MINN);
      float wxnf = fmaxf(sqrtf(s3v[2]), MINN);
      float psf = tan_k_((wxnf / xnadj) * artan_k_(xnadj, sq), sq) / wxnf;
      float pf2 = psf * psf * s3v[2];
      float xyp = psi * psf * s3v[3];
      float den3 = fmaxf(1.f - 2.f * kk * xyp + kk * kk * pi2 * pf2, MINN);
      float a3 = (1.f - 2.f * kk * xyp - kk * pf2) / den3;
      float b3 = (1.f + kk * pi2) / den3;
      float nc0 = a3 * psi * wxi0 + b3 * psf * wxf0;
      float nc1 = a3 * psi * wxi1 + b3 * psf * wxf1;
      float tc0 = tanhf(nc0), tc1 = tanhf(nc1);
      float s4v[1];
      s4v[0] = tc0 * tc0 + (full ? tc1 * tc1 : 0.f);
      block_reduce_sum8<1>(s4v, red);
      float unh = fmaxf(sqrtf(s4v[0]), MINN);
      float ehs = tan_k_(unh, sq) / unh;
      float Esq = ehs * ehs * s4v[0];
      float En = fmaxf(sqrtf(Esq), MINN);
      float wxo0 = gate0[2] * (ehs * tc0);
      float wxo1 = gate1[2] * (ehs * tc1);
      float s5v[1];
      s5v[0] = wxo0 * wxo0 + (full ? wxo1 * wxo1 : 0.f);
      block_reduce_sum8<1>(s5v, red);
      float wxno = fmaxf(sqrtf(s5v[0]), MINN);
      float pso = tan_k_((wxno / En) * artan_k_(En, sq), sq) / wxno;

      size_t BSHc = (size_t)BB * SS * 768;
      out[((size_t)r * SS + t) * 768 + j0] = gate0[2];
      float nh0 = pso * wxo0;
      cc0 = nc0; h_0 = nh0;
      ccT[j0 * 64 + r] = nc0;
      hT[j0 * 64 + r] = nh0;
      if (t == SS - 1) {
        out[BSHc + (size_t)r * 768 + j0] = nh0;
        out[BSHc + (size_t)BB * 768 + (size_t)r * 768 + j0] = nc0;
      }
      if (full) {
        out[((size_t)r * SS + t) * 768 + j1] = gate1[2];
        float nh1 = pso * wxo1;
        cc1 = nc1; h_1 = nh1;
        ccT[j1 * 64 + r] = nc1;
        hT[j1 * 64 + r] = nh1;
        if (t == SS - 1) {
          out[BSHc + (size_t)r * 768 + j1] = nh1;
          out[BSHc + (size_t)BB * 768 + (size_t)r * 768 + j1] = nc1;
        }
      }
    }
    gbar(bar, NWG * (++barn));
  }
}

extern "C" void kernel_launch(void* const* d_in, const int* in_sizes, int n_in,
                              void* d_out, int out_size, void* d_ws, size_t ws_size,
                              hipStream_t stream) {
  const float* inputs = (const float*)d_in[0];
  const float* ts = (const float*)d_in[1];
  const float* h0 = (const float*)d_in[2];
  const float* c0 = (const float*)d_in[3];
  const float* W_all = (const float*)d_in[4];
  const float* U_all = (const float*)d_in[5];
  const float* W_d = (const float*)d_in[6];
  const float* kptr = (const float*)d_in[7];
  float* ws = (float*)d_ws;
  float* out = (float*)d_out;

  size_t oBAR = 0;                               // 16 floats (64 B)
  size_t oCW = 16;
  size_t oCCT = oCW + (size_t)NWG * 12288;       // CW: 2,949,120 floats
  size_t oHT = oCCT + 49152;
  size_t oGOUT = oHT + 49152;
  size_t oXN = oGOUT + (size_t)BB * NCOL;
  size_t oUG = oXN + 8192;

  unsigned int* bar = (unsigned int*)(ws + oBAR);
  float* cw = ws + oCW;
  float* cct = ws + oCCT;
  float* ht = ws + oHT;
  float* gout = ws + oGOUT;
  float* xn = ws + oXN;
  __hip_bfloat16* ug = (__hip_bfloat16*)(ws + oUG);

  hipMemsetAsync(bar, 0, 64, stream);
  k_build_cw<<<NWG, 256, 0, stream>>>(W_all, W_d, cw);
  k_gemm_xu<<<dim3(128, 48), 256, 0, stream>>>(inputs, U_all, ug);
  k_xnorm<<<BB * SS, 256, 0, stream>>>(inputs, xn);

  void* args[] = {(void*)&cw, (void*)&cct, (void*)&ht,   (void*)&gout,
                  (void*)&ug, (void*)&xn,  (void*)&ts,   (void*)&kptr,
                  (void*)&h0, (void*)&c0,  (void*)&out,  (void*)&bar};
  hipLaunchCooperativeKernel((void*)k_scan, dim3(NWG), dim3(512), args, 0, stream);
}

// Round 4
// 10564.709 us; speedup vs baseline: 1.1102x; 1.0287x over previous
//
#include <hip/hip_runtime.h>
#include <hip/hip_bf16.h>
#include <math.h>

#define MINN 1e-7f

// Problem dims (fixed by setup_inputs)
#define BB 64
#define SS 128
#define NCOL 3840            // 768 (W_d) + 4*768 (gates)
#define NWG 240              // NCOL/16

__device__ __forceinline__ float artanh_c(float x) {
  x = fminf(fmaxf(x, -1.0f + 1e-6f), 1.0f - 1e-6f);
  return atanhf(x);
}
__device__ __forceinline__ float tan_k_(float x, float sq) { return tanhf(sq * x) / sq; }
__device__ __forceinline__ float artan_k_(float x, float sq) { return artanh_c(sq * x) / sq; }

// Block reduction over 512 threads (8 waves).
template <int N>
__device__ __forceinline__ void block_reduce_sum8(float* v, float* red) {
#pragma unroll
  for (int m = 1; m < 64; m <<= 1) {
#pragma unroll
    for (int i = 0; i < N; ++i) v[i] += __shfl_xor(v[i], m, 64);
  }
  int wid = threadIdx.x >> 6;
  int lane = threadIdx.x & 63;
  if (lane == 0) {
#pragma unroll
    for (int i = 0; i < N; ++i) red[wid * N + i] = v[i];
  }
  __syncthreads();
#pragma unroll
  for (int i = 0; i < N; ++i) {
    float s = 0.f;
#pragma unroll
    for (int w = 0; w < 8; ++w) s += red[w * N + i];
    v[i] = s;
  }
  __syncthreads();
}

// Contention-free grid barrier: per-WG generation flags.
// Arrive: one release-store to own flag (no RMW, no shared-counter contention).
// Wait: threads 0..NWG-1 each poll ONE flag for >= gen (monotonic, no reset).
__device__ __forceinline__ void gbar(unsigned int* flags, unsigned int gen, bool wrote) {
  __syncthreads();  // drains all waves' vmem (compiler emits vmcnt(0) before s_barrier)
  if (threadIdx.x == 0) {
    if (wrote) __threadfence();  // release: writeback so other XCDs see our data
    __hip_atomic_store(&flags[blockIdx.x], gen, __ATOMIC_RELEASE, __HIP_MEMORY_SCOPE_AGENT);
  }
  if (threadIdx.x < NWG) {
    while (__hip_atomic_load(&flags[threadIdx.x], __ATOMIC_RELAXED,
                             __HIP_MEMORY_SCOPE_AGENT) < gen) {
      __builtin_amdgcn_s_sleep(1);
    }
  }
  __syncthreads();
  if (threadIdx.x == 0) __threadfence();  // acquire: invalidate stale L1/L2
  __syncthreads();
}

// Build combined weight matrix, chunked: CW[j][k][cc] = weight(k, col=j*16+cc)
__global__ __launch_bounds__(256) void k_build_cw(const float* __restrict__ W_all,
                                                  const float* __restrict__ W_d,
                                                  float* __restrict__ CW) {
  int j = blockIdx.x;
  float* dst = CW + (size_t)j * 12288;
  for (int idx = threadIdx.x; idx < 12288; idx += 256) {
    int k = idx >> 4;
    int cc = idx & 15;
    int col = j * 16 + cc;
    float v;
    if (col < 768) {
      v = W_d[col * 768 + k];
    } else {
      int jm = col - 768;
      int g = jm / 768;
      int j2 = jm - g * 768;
      v = W_all[j2 * 3072 + g * 768 + k];
    }
    dst[idx] = v;
  }
}

__global__ __launch_bounds__(256) void k_xnorm(const float* __restrict__ X,
                                               float* __restrict__ XN) {
  __shared__ float red[4];
  int r = blockIdx.x;
  float s = 0.f;
#pragma unroll
  for (int p = 0; p < 3; ++p) {
    float v = X[(size_t)r * 768 + threadIdx.x + 256 * p];
    s += v * v;
  }
#pragma unroll
  for (int m = 1; m < 64; m <<= 1) s += __shfl_xor(s, m, 64);
  if ((threadIdx.x & 63) == 0) red[threadIdx.x >> 6] = s;
  __syncthreads();
  if (threadIdx.x == 0) XN[r] = fmaxf(sqrtf(red[0] + red[1] + red[2] + red[3]), MINN);
}

// C[i][m] = sum_k X[i][k] * U[m][k];  M=8192, N=3072, K=768. Output bf16.
__global__ __launch_bounds__(256) void k_gemm_xu(const float* __restrict__ X,
                                                 const float* __restrict__ U,
                                                 __hip_bfloat16* __restrict__ OUT) {
  __shared__ float As[64][17];
  __shared__ float Bs[64][17];
  int tid = threadIdx.x;
  int lr = tid >> 2;
  int lk = (tid & 3) * 4;
  int tm = tid & 15;
  int ti = tid >> 4;
  const float* xr = X + (size_t)(blockIdx.x * 64 + lr) * 768 + lk;
  const float* ur = U + (size_t)(blockIdx.y * 64 + lr) * 768 + lk;
  float acc[4][4];
#pragma unroll
  for (int a = 0; a < 4; ++a)
#pragma unroll
    for (int b = 0; b < 4; ++b) acc[a][b] = 0.f;

  for (int kt = 0; kt < 768; kt += 16) {
    float4 a = *(const float4*)(xr + kt);
    float4 b = *(const float4*)(ur + kt);
    As[lr][lk + 0] = a.x; As[lr][lk + 1] = a.y; As[lr][lk + 2] = a.z; As[lr][lk + 3] = a.w;
    Bs[lr][lk + 0] = b.x; Bs[lr][lk + 1] = b.y; Bs[lr][lk + 2] = b.z; Bs[lr][lk + 3] = b.w;
    __syncthreads();
#pragma unroll
    for (int k = 0; k < 16; ++k) {
      float av[4], bv[4];
#pragma unroll
      for (int q = 0; q < 4; ++q) {
        av[q] = As[ti * 4 + q][k];
        bv[q] = Bs[tm * 4 + q][k];
      }
#pragma unroll
      for (int rr = 0; rr < 4; ++rr)
#pragma unroll
        for (int c2 = 0; c2 < 4; ++c2) acc[rr][c2] += av[rr] * bv[c2];
    }
    __syncthreads();
  }
#pragma unroll
  for (int rr = 0; rr < 4; ++rr)
#pragma unroll
    for (int c2 = 0; c2 < 4; ++c2)
      OUT[(size_t)(blockIdx.x * 64 + ti * 4 + rr) * 3072 + blockIdx.y * 64 + tm * 4 + c2] =
          __float2bfloat16(acc[rr][c2]);
}

// Persistent scan: 240 WGs x 512 threads, flag-array grid barrier.
// Phase A (all WGs): 16 cols each, k split across thread halves, 2-deep load pipeline.
// Phase B (WGs 0..63): hyperbolic pointwise update; c/h state in registers (2 elem/thread).
__global__ __launch_bounds__(512, 1) void k_scan(
    const float* __restrict__ CW, float* __restrict__ ccT, float* __restrict__ hT,
    float* __restrict__ GOUT, const __hip_bfloat16* __restrict__ UG,
    const float* __restrict__ XN, const float* __restrict__ TS,
    const float* __restrict__ kptr, const float* __restrict__ h0,
    const float* __restrict__ c0, float* __restrict__ out, unsigned int* __restrict__ flags) {
  __shared__ float Wl[12288];    // 48 KB weight chunk, resident across all steps
  __shared__ float4 Pacc[512];   // 8 KB phase-A partial combine
  __shared__ float red[8 * 15];  // reductions
  int wg = blockIdx.x;
  int tid = threadIdx.x;

  // Load this WG's weight chunk once (512 threads x 6 float4).
  {
    const float4* s4 = (const float4*)(CW + (size_t)wg * 12288);
    float4* d4 = (float4*)Wl;
#pragma unroll
    for (int it = 0; it < 6; ++it) d4[tid + 512 * it] = s4[tid + 512 * it];
  }

  float kk = kptr[0];
  float sq = sqrtf(-kk);
  int r = wg;                 // row owned in phase B (wg < 64 only)
  bool full = tid < 256;      // second element (j1) valid
  int j0 = tid, j1 = 512 + tid;

  // Register-resident recurrent state for phase B owners.
  float cc0 = 0.f, cc1 = 0.f, h_0 = 0.f, h_1 = 0.f;
  if (wg < BB) {
    cc0 = c0[r * 768 + j0];
    h_0 = h0[r * 768 + j0];
    ccT[j0 * 64 + r] = cc0;
    hT[j0 * 64 + r] = h_0;
    if (full) {
      cc1 = c0[r * 768 + j1];
      h_1 = h0[r * 768 + j1];
      ccT[j1 * 64 + r] = cc1;
      hT[j1 * 64 + r] = h_1;
    }
  }
  unsigned int barn = 0;
  gbar(flags, ++barn, wg < BB);

  for (int t = 0; t < SS; ++t) {
    // ---------------- Phase A: recurrent GEMM (all 240 WGs) ----------------
    {
      const float* src = (wg < 48) ? ccT : hT;
      int c = tid & 15;
      int rg = (tid >> 4) & 15;
      int kh = tid >> 8;  // 0 or 1: k-half
      const float4* sp = ((const float4*)src) + rg;  // element k at sp[k*16]
      const int kbase = kh * 384;
      float a0 = 0.f, a1 = 0.f, a2 = 0.f, a3 = 0.f;
      float4 bufA[8], bufB[8];
#pragma unroll
      for (int i = 0; i < 8; ++i) bufA[i] = sp[(kbase + i) * 16];
      for (int kb = 0; kb < 48; kb += 2) {
#pragma unroll
        for (int i = 0; i < 8; ++i) bufB[i] = sp[(kbase + (kb + 1) * 8 + i) * 16];
#pragma unroll
        for (int i = 0; i < 8; ++i) {
          int k = kbase + kb * 8 + i;
          float w = Wl[k * 16 + c];
          a0 += bufA[i].x * w; a1 += bufA[i].y * w; a2 += bufA[i].z * w; a3 += bufA[i].w * w;
        }
        if (kb + 2 < 48) {
#pragma unroll
          for (int i = 0; i < 8; ++i) bufA[i] = sp[(kbase + (kb + 2) * 8 + i) * 16];
        }
#pragma unroll
        for (int i = 0; i < 8; ++i) {
          int k = kbase + (kb + 1) * 8 + i;
          float w = Wl[k * 16 + c];
          a0 += bufB[i].x * w; a1 += bufB[i].y * w; a2 += bufB[i].z * w; a3 += bufB[i].w * w;
        }
      }
      Pacc[tid] = make_float4(a0, a1, a2, a3);
      __syncthreads();
      if (tid < 256) {
        float4 p0 = Pacc[tid];
        float4 p1 = Pacc[tid + 256];
        int col = wg * 16 + (tid & 15);
        int rg2 = tid >> 4;
        GOUT[(4 * rg2 + 0) * NCOL + col] = p0.x + p1.x;
        GOUT[(4 * rg2 + 1) * NCOL + col] = p0.y + p1.y;
        GOUT[(4 * rg2 + 2) * NCOL + col] = p0.z + p1.z;
        GOUT[(4 * rg2 + 3) * NCOL + col] = p0.w + p1.w;
      }
    }
    gbar(flags, ++barn, true);

    // ---------------- Phase B: pointwise hyperbolic update (WGs 0..63) ------
    if (wg < BB) {
      const float* grow = GOUT + r * NCOL;
      int i = r * SS + t;
      const __hip_bfloat16* urow = UG + (size_t)i * 3072;

      float mv0, mv1, gh0[4], gh1[4], mx0[4], mx1[4];
      mv0 = grow[j0];
      mv1 = full ? grow[j1] : 0.f;
#pragma unroll
      for (int g = 0; g < 4; ++g) {
        gh0[g] = grow[768 + g * 768 + j0];
        gh1[g] = full ? grow[768 + g * 768 + j1] : 0.f;
        mx0[g] = __bfloat162float(urow[g * 768 + j0]);
        mx1[g] = full ? __bfloat162float(urow[g * 768 + j1]) : 0.f;
      }

      // batch1: {c2, h2, mvn2, |gh_g|^2 x4, gh_g.mx_g x4, |mx_g|^2 x4}
      float sv[15];
#pragma unroll
      for (int q = 0; q < 15; ++q) sv[q] = 0.f;
      sv[0] = cc0 * cc0 + cc1 * cc1;
      sv[1] = h_0 * h_0 + h_1 * h_1;
      sv[2] = mv0 * mv0 + mv1 * mv1;
#pragma unroll
      for (int g = 0; g < 4; ++g) {
        sv[3 + g] = gh0[g] * gh0[g] + gh1[g] * gh1[g];
        sv[7 + g] = gh0[g] * mx0[g] + gh1[g] * mx1[g];
        sv[11 + g] = mx0[g] * mx0[g] + mx1[g] * mx1[g];
      }
      block_reduce_sum8<15>(sv, red);
      float c2 = sv[0], h2 = sv[1], mvn2 = sv[2];
      float xn_c = fmaxf(sqrtf(c2), MINN);
      float xn_h = fmaxf(sqrtf(h2), MINN);
      float mxn_d = fmaxf(sqrtf(mvn2), MINN);

      // W_d path
      float r_d = (mxn_d / xn_c) * artan_k_(xn_c, sq);
      float twd = tan_k_(r_d, sq);
      float wdsc = twd / mxn_d;
      float yn_d = fmaxf(fabsf(twd), MINN);
      float lsc = (artan_k_(yn_d, sq) / yn_d) * wdsc;
      float th0 = tanhf(lsc * mv0);
      float th1 = tanhf(lsc * mv1);

      // gates
      float uxn = XN[i];
      float ak_h = artan_k_(xn_h, sq);
      float ak_u = artan_k_(uxn, sq);
      float cAg[4], cBg[4], pscg[4];
#pragma unroll
      for (int g = 0; g < 4; ++g) {
        float ghn = fmaxf(sqrtf(sv[3 + g]), MINN);
        float tg = tan_k_((ghn / xn_h) * ak_h, sq);
        float wsc = tg / ghn;
        float w2 = tg * tg;
        float umxn = fmaxf(sqrtf(sv[11 + g]), MINN);
        float us = tan_k_((umxn / uxn) * ak_u, sq) / umxn;
        float u2 = us * us * sv[11 + g];
        float xy = wsc * us * sv[7 + g];
        float den = fmaxf(1.f - 2.f * kk * xy + kk * kk * w2 * u2, MINN);
        float a = (1.f - 2.f * kk * xy - kk * u2) / den;
        float b = (1.f + kk * w2) / den;
        float y2s = fmaxf(a * a * w2 + 2.f * a * b * xy + b * b * u2, 0.f);
        float yn = fmaxf(sqrtf(y2s), MINN);
        pscg[g] = artan_k_(yn, sq) / yn;
        cAg[g] = a * wsc;
        cBg[g] = b * us;
      }
      float gate0[4], gate1[4];
#pragma unroll
      for (int g = 0; g < 4; ++g) {
        gate0[g] = 1.f / (1.f + expf(-pscg[g] * (cAg[g] * gh0[g] + cBg[g] * mx0[g])));
        gate1[g] = 1.f / (1.f + expf(-pscg[g] * (cAg[g] * gh1[g] + cBg[g] * mx1[g])));
      }

      // batch2: {|th|^2, th.cc}
      float s2v[2];
      s2v[0] = th0 * th0 + th1 * th1;
      s2v[1] = th0 * cc0 + th1 * cc1;
      block_reduce_sum8<2>(s2v, red);
      float un = fmaxf(sqrtf(s2v[0]), MINN);
      float esc = tan_k_(un, sq) / un;
      float cs1_0 = esc * th0, cs1_1 = esc * th1;
      float d1 = esc * s2v[1];
      float s1sq = esc * esc * s2v[0];

      // c_s2 = s2s * cs1
      float tv = TS[r * SS + t];
      float xnt = fmaxf(sqrtf(768.f * tv * tv), MINN);
      float wxn_t = fmaxf(fabsf(tv) * sqrtf(s1sq), MINN);
      float s2s = tan_k_((wxn_t / xnt) * artan_k_(xnt, sq), sq) / wxn_t * tv;
      float s2sq = s2s * s2s * s1sq;

      // c_l = mobius_add(-cs1, cc)
      float den_l = fmaxf(1.f + 2.f * kk * d1 + kk * kk * s1sq * c2, MINN);
      float al = (1.f + 2.f * kk * d1 - kk * c2) / den_l;
      float bl = (1.f + kk * s1sq) / den_l;
      float pcl = -al, qcl = bl;

      // c_adj = mobius_add(c_l, c_s2)
      float xy2 = s2s * (pcl * s1sq + qcl * d1);
      float x2b = fmaxf(pcl * pcl * s1sq + 2.f * pcl * qcl * d1 + qcl * qcl * c2, 0.f);
      float y2b = s2sq;
      float den2 = fmaxf(1.f - 2.f * kk * xy2 + kk * kk * x2b * y2b, MINN);
      float a2 = (1.f - 2.f * kk * xy2 - kk * y2b) / den2;
      float b2 = (1.f + kk * x2b) / den2;
      float g1c = a2 * pcl + b2 * s2s;
      float g2c = a2 * qcl;
      float cadj0 = g1c * cs1_0 + g2c * cc0;
      float cadj1 = g1c * cs1_1 + g2c * cc1;
      float adjsq = fmaxf(g1c * g1c * s1sq + 2.f * g1c * g2c * d1 + g2c * g2c * c2, 0.f);

      // new_c = madd(pmul(i,c_tmp), pmul(f,c_adj))
      float wxi0 = gate0[1] * gate0[3], wxi1 = gate1[1] * gate1[3];
      float wxf0 = gate0[0] * cadj0, wxf1 = gate1[0] * cadj1;
      float s3v[4];
      s3v[0] = gate0[3] * gate0[3];
      s3v[1] = wxi0 * wxi0;
      s3v[2] = wxf0 * wxf0;
      s3v[3] = wxi0 * wxf0;
      if (full) {
        s3v[0] += gate1[3] * gate1[3];
        s3v[1] += wxi1 * wxi1;
        s3v[2] += wxf1 * wxf1;
        s3v[3] += wxi1 * wxf1;
      }
      block_reduce_sum8<4>(s3v, red);
      float xnct = fmaxf(sqrtf(s3v[0]), MINN);
      float wxni = fmaxf(sqrtf(s3v[1]), MINN);
      float psi = tan_k_((wxni / xnct) * artan_k_(xnct, sq), sq) / wxni;
      float pi2 = psi * psi * s3v[1];
      float xnadj = fmaxf(sqrtf(adjsq), MINN);
      float wxnf = fmaxf(sqrtf(s3v[2]), MINN);
      float psf = tan_k_((wxnf / xnadj) * artan_k_(xnadj, sq), sq) / wxnf;
      float pf2 = psf * psf * s3v[2];
      float xyp = psi * psf * s3v[3];
      float den3 = fmaxf(1.f - 2.f * kk * xyp + kk * kk * pi2 * pf2, MINN);
      float a3 = (1.f - 2.f * kk * xyp - kk * pf2) / den3;
      float b3 = (1.f + kk * pi2) / den3;
      float nc0 = a3 * psi * wxi0 + b3 * psf * wxf0;
      float nc1 = a3 * psi * wxi1 + b3 * psf * wxf1;
      float tc0 = tanhf(nc0), tc1 = tanhf(nc1);
      float s4v[1];
      s4v[0] = tc0 * tc0 + (full ? tc1 * tc1 : 0.f);
      block_reduce_sum8<1>(s4v, red);
      float unh = fmaxf(sqrtf(s4v[0]), MINN);
      float ehs = tan_k_(unh, sq) / unh;
      float Esq = ehs * ehs * s4v[0];
      float En = fmaxf(sqrtf(Esq), MINN);
      float wxo0 = gate0[2] * (ehs * tc0);
      float wxo1 = gate1[2] * (ehs * tc1);
      float s5v[1];
      s5v[0] = wxo0 * wxo0 + (full ? wxo1 * wxo1 : 0.f);
      block_reduce_sum8<1>(s5v, red);
      float wxno = fmaxf(sqrtf(s5v[0]), MINN);
      float pso = tan_k_((wxno / En) * artan_k_(En, sq), sq) / wxno;

      size_t BSHc = (size_t)BB * SS * 768;
      out[((size_t)r * SS + t) * 768 + j0] = gate0[2];
      float nh0 = pso * wxo0;
      cc0 = nc0; h_0 = nh0;
      ccT[j0 * 64 + r] = nc0;
      hT[j0 * 64 + r] = nh0;
      if (t == SS - 1) {
        out[BSHc + (size_t)r * 768 + j0] = nh0;
        out[BSHc + (size_t)BB * 768 + (size_t)r * 768 + j0] = nc0;
      }
      if (full) {
        out[((size_t)r * SS + t) * 768 + j1] = gate1[2];
        float nh1 = pso * wxo1;
        cc1 = nc1; h_1 = nh1;
        ccT[j1 * 64 + r] = nc1;
        hT[j1 * 64 + r] = nh1;
        if (t == SS - 1) {
          out[BSHc + (size_t)r * 768 + j1] = nh1;
          out[BSHc + (size_t)BB * 768 + (size_t)r * 768 + j1] = nc1;
        }
      }
    }
    if (t < SS - 1) {
      gbar(flags, ++barn, wg < BB);
    }
  }
}

extern "C" void kernel_launch(void* const* d_in, const int* in_sizes, int n_in,
                              void* d_out, int out_size, void* d_ws, size_t ws_size,
                              hipStream_t stream) {
  const float* inputs = (const float*)d_in[0];
  const float* ts = (const float*)d_in[1];
  const float* h0 = (const float*)d_in[2];
  const float* c0 = (const float*)d_in[3];
  const float* W_all = (const float*)d_in[4];
  const float* U_all = (const float*)d_in[5];
  const float* W_d = (const float*)d_in[6];
  const float* kptr = (const float*)d_in[7];
  float* ws = (float*)d_ws;
  float* out = (float*)d_out;

  size_t oBAR = 0;                               // 256 uints (1 KB) of flags
  size_t oCW = 256;
  size_t oCCT = oCW + (size_t)NWG * 12288;       // CW: 2,949,120 floats
  size_t oHT = oCCT + 49152;
  size_t oGOUT = oHT + 49152;
  size_t oXN = oGOUT + (size_t)BB * NCOL;
  size_t oUG = oXN + 8192;

  unsigned int* flags = (unsigned int*)(ws + oBAR);
  float* cw = ws + oCW;
  float* cct = ws + oCCT;
  float* ht = ws + oHT;
  float* gout = ws + oGOUT;
  float* xn = ws + oXN;
  __hip_bfloat16* ug = (__hip_bfloat16*)(ws + oUG);

  hipMemsetAsync(flags, 0, 1024, stream);
  k_build_cw<<<NWG, 256, 0, stream>>>(W_all, W_d, cw);
  k_gemm_xu<<<dim3(128, 48), 256, 0, stream>>>(inputs, U_all, ug);
  k_xnorm<<<BB * SS, 256, 0, stream>>>(inputs, xn);

  void* args[] = {(void*)&cw, (void*)&cct, (void*)&ht,   (void*)&gout,
                  (void*)&ug, (void*)&xn,  (void*)&ts,   (void*)&kptr,
                  (void*)&h0, (void*)&c0,  (void*)&out,  (void*)&flags};
  hipLaunchCooperativeKernel((void*)k_scan, dim3(NWG), dim3(512), args, 0, stream);
}